// Round 1
// 20228.044 us; speedup vs baseline: 1.0150x; 1.0150x over previous
//
#include <hip/hip_runtime.h>

#define T_STEPS 2048
#define NBATCH  32
#define IN_DIM  64
#define RES     1024
#define LEAKF   0.3f
#define NCG     64   // column groups (16 cols each)
#define NBG     4    // batch groups (8 batches each)

typedef unsigned long long u64cp;

// ---------------------------------------------------------------------------
// Persistent kernel: entire T-loop on-device. Grid (64,4) = 256 blocks, one
// per CU (capacity >= 2 blocks/CU, so co-residency is guaranteed for a plain
// launch). W_res column-slices live in registers for the whole run.
// Cross-block state exchange: agent-scope (sc1) stores/loads via MALL; per
// batch-group 64-entry flag array, monotonically increasing step counters.
// ---------------------------------------------------------------------------
__global__ __launch_bounds__(256, 1) void esn_persist(
    const float* __restrict__ inp,   // [32][2048][64]
    const float* __restrict__ Win,   // [64][1024]
    const float* __restrict__ Wres,  // [1024][1024]
    float* __restrict__ out,         // [32][2048][1024]
    float* __restrict__ sT,          // ws: [2][1024][32] state, k-major
    unsigned* __restrict__ flags)    // ws: [4][64] step flags
{
    const int tid   = threadIdx.x;
    const int c_loc = tid & 15;
    const int ks    = tid >> 4;            // 0..15 : k-chunk [64*ks, 64*ks+64)
    const int cg    = blockIdx.x;          // 0..63
    const int bg    = blockIdx.y;          // 0..3
    const int c0    = cg * 16;
    const int b0    = bg * 8;
    const int c     = c0 + c_loc;

    // Hoist this thread's Wres slice into registers: w[j] = Wres[ks*64+j][c].
    float w[64];
    {
        const float* wp = Wres + (size_t)(ks * 64) * RES + c;
        #pragma unroll
        for (int j = 0; j < 64; ++j) w[j] = wp[(size_t)j * RES];
    }

    __shared__ float pl[16][8][17];        // k-partials; <=2-way bank aliased
    unsigned* flg = flags + bg * NCG;      // this batch-group's 64 flags

    // Finalize-thread identity (valid for tid < 128): batch fb, column c.
    const int fb = tid >> 4;               // 0..7
    float s_prev = 0.f;                    // register-carried state (b0+fb, c)

    for (int t = 0; t < T_STEPS; ++t) {
        float* sTr = sT + ((t & 1) ^ 1) * (RES * NBATCH);  // state t-1
        float* sTw = sT + (t & 1) * (RES * NBATCH);        // state t

        // ---- Phase A: input projection (independent of state; overlaps wait)
        float x = 0.f;
        if (tid < 128) {
            const float* inb = inp + ((size_t)(b0 + fb) * T_STEPS + t) * IN_DIM;
            #pragma unroll 8
            for (int i = 0; i < IN_DIM; ++i)
                x = fmaf(inb[i], Win[(size_t)i * RES + c], x);
        }

        // ---- Phase B: wait until all 64 producer blocks finished step t-1.
        if (t > 0) {
            if (tid < NCG) {
                const unsigned tgt = (unsigned)t;
                while (__hip_atomic_load(&flg[tid], __ATOMIC_RELAXED,
                                         __HIP_MEMORY_SCOPE_AGENT) < tgt) { }
            }
            __syncthreads();   // compiler+wave barrier: loads below can't hoist
        }

        // ---- Phase C: acc(b) = sum over this thread's k-chunk of W[k][c]*s[k][b]
        float acc0 = 0.f, acc1 = 0.f, acc2 = 0.f, acc3 = 0.f;
        float acc4 = 0.f, acc5 = 0.f, acc6 = 0.f, acc7 = 0.f;
        if (t > 0) {
            float* sp = sTr + (size_t)(ks * 64) * NBATCH + b0;
            #pragma unroll
            for (int j = 0; j < 64; ++j) {
                u64cp p01 = __hip_atomic_load((u64cp*)(sp + (size_t)j * NBATCH + 0),
                                              __ATOMIC_RELAXED, __HIP_MEMORY_SCOPE_AGENT);
                u64cp p23 = __hip_atomic_load((u64cp*)(sp + (size_t)j * NBATCH + 2),
                                              __ATOMIC_RELAXED, __HIP_MEMORY_SCOPE_AGENT);
                u64cp p45 = __hip_atomic_load((u64cp*)(sp + (size_t)j * NBATCH + 4),
                                              __ATOMIC_RELAXED, __HIP_MEMORY_SCOPE_AGENT);
                u64cp p67 = __hip_atomic_load((u64cp*)(sp + (size_t)j * NBATCH + 6),
                                              __ATOMIC_RELAXED, __HIP_MEMORY_SCOPE_AGENT);
                const float wj = w[j];
                acc0 = fmaf(__uint_as_float((unsigned)(p01       )), wj, acc0);
                acc1 = fmaf(__uint_as_float((unsigned)(p01 >> 32u)), wj, acc1);
                acc2 = fmaf(__uint_as_float((unsigned)(p23       )), wj, acc2);
                acc3 = fmaf(__uint_as_float((unsigned)(p23 >> 32u)), wj, acc3);
                acc4 = fmaf(__uint_as_float((unsigned)(p45       )), wj, acc4);
                acc5 = fmaf(__uint_as_float((unsigned)(p45 >> 32u)), wj, acc5);
                acc6 = fmaf(__uint_as_float((unsigned)(p67       )), wj, acc6);
                acc7 = fmaf(__uint_as_float((unsigned)(p67 >> 32u)), wj, acc7);
            }
        }

        // ---- Phase D: 16-way k-reduce through LDS, then finalize (tanh/leak).
        pl[ks][0][c_loc] = acc0;
        pl[ks][1][c_loc] = acc1;
        pl[ks][2][c_loc] = acc2;
        pl[ks][3][c_loc] = acc3;
        pl[ks][4][c_loc] = acc4;
        pl[ks][5][c_loc] = acc5;
        pl[ks][6][c_loc] = acc6;
        pl[ks][7][c_loc] = acc7;
        __syncthreads();

        if (tid < 128) {
            float sum = 0.f;
            #pragma unroll
            for (int q = 0; q < 16; ++q) sum += pl[q][fb][c_loc];

            const float nw = tanhf(x + sum);
            const float sn = fmaf(1.0f - LEAKF, s_prev, LEAKF * nw);
            s_prev = sn;

            out[((size_t)(b0 + fb) * T_STEPS + t) * RES + c] = sn;
            // agent-scope store: goes straight to the device coherence point
            __hip_atomic_store(sTw + (size_t)c * NBATCH + (b0 + fb), sn,
                               __ATOMIC_RELAXED, __HIP_MEMORY_SCOPE_AGENT);
        }
        __syncthreads();   // each wave drains vmcnt(0) here -> state globally visible

        // ---- Phase E: publish completion of step t.
        if (tid == 0)
            __hip_atomic_store(&flg[cg], (unsigned)(t + 1),
                               __ATOMIC_RELAXED, __HIP_MEMORY_SCOPE_AGENT);
    }
}

// ---------------------------------------------------------------------------
// Fallback: previous proven per-step kernel (used only if ws too small).
// ---------------------------------------------------------------------------
__global__ __launch_bounds__(256) void esn_step(
    const float* __restrict__ inp,
    const float* __restrict__ Win,
    const float* __restrict__ Wres,
    float* __restrict__ out,
    float* __restrict__ sT,
    int t)
{
    const int tid   = threadIdx.x;
    const int c_loc = tid & 15;
    const int ks    = tid >> 4;
    const int c0    = blockIdx.x * 16;
    const int b0    = blockIdx.y * 8;
    const int c     = c0 + c_loc;

    const float* sTr = sT + ((t & 1) ^ 1) * (RES * NBATCH);
    float*       sTw = sT + (t & 1) * (RES * NBATCH);

    float acc0 = 0.f, acc1 = 0.f, acc2 = 0.f, acc3 = 0.f;
    float acc4 = 0.f, acc5 = 0.f, acc6 = 0.f, acc7 = 0.f;

    if (t > 0) {
        const int kbeg = ks * 64;
        const float* wp = Wres + (size_t)kbeg * RES + c;
        const float* sp = sTr + kbeg * NBATCH + b0;
        #pragma unroll 4
        for (int j = 0; j < 64; ++j) {
            const float w = wp[(size_t)j * RES];
            const float4 sa = *reinterpret_cast<const float4*>(sp + j * NBATCH);
            const float4 sb = *reinterpret_cast<const float4*>(sp + j * NBATCH + 4);
            acc0 = fmaf(sa.x, w, acc0);
            acc1 = fmaf(sa.y, w, acc1);
            acc2 = fmaf(sa.z, w, acc2);
            acc3 = fmaf(sa.w, w, acc3);
            acc4 = fmaf(sb.x, w, acc4);
            acc5 = fmaf(sb.y, w, acc5);
            acc6 = fmaf(sb.z, w, acc6);
            acc7 = fmaf(sb.w, w, acc7);
        }
    }

    __shared__ float pl[16][8][17];
    pl[ks][0][c_loc] = acc0;
    pl[ks][1][c_loc] = acc1;
    pl[ks][2][c_loc] = acc2;
    pl[ks][3][c_loc] = acc3;
    pl[ks][4][c_loc] = acc4;
    pl[ks][5][c_loc] = acc5;
    pl[ks][6][c_loc] = acc6;
    pl[ks][7][c_loc] = acc7;
    __syncthreads();

    if (tid < 128) {
        const int b  = tid >> 4;
        const int cl = tid & 15;
        const int cg = c0 + cl;
        const int bg = b0 + b;

        float sum = 0.f;
        #pragma unroll
        for (int q = 0; q < 16; ++q) sum += pl[q][b][cl];

        const float* inb = inp + ((size_t)bg * T_STEPS + t) * IN_DIM;
        float x = 0.f;
        #pragma unroll 8
        for (int i = 0; i < IN_DIM; ++i)
            x = fmaf(inb[i], Win[(size_t)i * RES + cg], x);

        const float a  = x + sum;
        const float nw = tanhf(a);
        const float spv = (t > 0) ? sTr[cg * NBATCH + bg] : 0.f;
        const float sn = fmaf(1.0f - LEAKF, spv, LEAKF * nw);

        out[((size_t)bg * T_STEPS + t) * RES + cg] = sn;
        sTw[cg * NBATCH + bg] = sn;
    }
}

extern "C" void kernel_launch(void* const* d_in, const int* in_sizes, int n_in,
                              void* d_out, int out_size, void* d_ws, size_t ws_size,
                              hipStream_t stream)
{
    const float* inp  = (const float*)d_in[0];   // [32,2048,64]
    const float* Win  = (const float*)d_in[1];   // [64,1024]
    const float* Wres = (const float*)d_in[2];   // [1024,1024]
    float* out = (float*)d_out;                  // [32,2048,1024]
    float* sT  = (float*)d_ws;                   // [2][1024][32] state

    const size_t stateBytes = (size_t)2 * RES * NBATCH * sizeof(float);  // 256 KB
    const size_t flagBytes  = (size_t)NBG * NCG * sizeof(unsigned);      // 1 KB

    if (ws_size >= stateBytes + flagBytes) {
        unsigned* flags = (unsigned*)((char*)d_ws + stateBytes);
        hipMemsetAsync(flags, 0, flagBytes, stream);   // re-zeroed every replay
        hipLaunchKernelGGL(esn_persist, dim3(NCG, NBG), dim3(256), 0, stream,
                           inp, Win, Wres, out, sT, flags);
        return;
    }

    // Workspace too small for flags: proven per-step path.
    dim3 grid(64, 4), blk(256);
    for (int t = 0; t < T_STEPS; ++t) {
        hipLaunchKernelGGL(esn_step, grid, blk, 0, stream,
                           inp, Win, Wres, out, sT, t);
    }
}